// Round 9
// baseline (223.364 us; speedup 1.0000x reference)
//
#include <hip/hip_runtime.h>
#include <hip/hip_bf16.h>

#define DEV __device__ __forceinline__

typedef short bf16x8 __attribute__((ext_vector_type(8)));
typedef float f32x4 __attribute__((ext_vector_type(4)));
typedef float f32x16 __attribute__((ext_vector_type(16)));
typedef unsigned int u32;

constexpr int BB = 2, SS = 2048, DD = 1024, HH = 16, DHD = 64;
constexpr int MM = BB * SS; // 4096
#define QSC 0.1803368801111f  /* 0.125 * log2(e): scores in log2 domain */

#if __has_builtin(__builtin_amdgcn_exp2f)
#define EXP2(x) __builtin_amdgcn_exp2f(x)
#else
#define EXP2(x) exp2f(x)
#endif

// round-half-up bf16; bias only at exact-half cases
DEV unsigned short f2bf(float f) {
    union { float f; unsigned int u; } v; v.f = f;
    return (unsigned short)((v.u + 0x8000u) >> 16);
}
// pack two f32 -> (bf16(b)<<16)|bf16(a) : add, add, v_perm = 3 instr
#if __has_builtin(__builtin_amdgcn_perm)
DEV u32 pk2bf(float a, float b) {
    union { float f; u32 u; } ua, ub; ua.f = a; ub.f = b;
    return __builtin_amdgcn_perm(ub.u + 0x8000u, ua.u + 0x8000u, 0x07060302u);
}
#else
DEV u32 pk2bf(float a, float b) {
    union { float f; u32 u; } ua, ub; ua.f = a; ub.f = b;
    return ((ua.u + 0x8000u) >> 16) | ((ub.u + 0x8000u) & 0xffff0000u);
}
#endif

DEV bf16x8 ld_bf16x8(const unsigned short* p) { return *(const bf16x8*)p; }

// async global->LDS, 16B per lane; lds dest = wave-uniform base + lane*16
DEV void gl16(const unsigned short* g, unsigned short* l) {
    __builtin_amdgcn_global_load_lds(
        (const __attribute__((address_space(1))) u32*)g,
        (__attribute__((address_space(3))) u32*)l, 16, 0, 0);
}

// ---- prep (fused): blocks [0,4096) = x->bf16 ; [4096,8192) = W transposes ----
__global__ void prep(const float* __restrict__ x, unsigned short* __restrict__ xb,
                     const float* __restrict__ W0, const float* __restrict__ W1,
                     const float* __restrict__ W2, const float* __restrict__ W3,
                     unsigned short* __restrict__ WtBase) {
    __shared__ float tile[32][33];
    int blk = blockIdx.x;
    if (blk < 4096) {
        int i = blk * 256 + threadIdx.x;
        float4 v = ((const float4*)x)[i];
        uint2 o;
        o.x = pk2bf(v.x, v.y);
        o.y = pk2bf(v.z, v.w);
        ((uint2*)xb)[i] = o;
        return;
    }
    blk -= 4096;                 // 4 weights x 1024 tiles
    int wsel = blk >> 10;
    const float* W = (wsel == 0) ? W0 : (wsel == 1) ? W1 : (wsel == 2) ? W2 : W3;
    unsigned short* Wt = WtBase + (size_t)wsel * DD * DD;
    int t = blk & 1023;
    int n0 = (t & 31) * 32, k0 = (t >> 5) * 32;
    int tx = threadIdx.x & 31, ty = threadIdx.x >> 5; // 32 x 8
    #pragma unroll
    for (int i = 0; i < 4; ++i)
        tile[ty + 8 * i][tx] = W[(size_t)(k0 + ty + 8 * i) * DD + n0 + tx];
    __syncthreads();
    #pragma unroll
    for (int i = 0; i < 4; ++i)
        Wt[(size_t)(n0 + ty + 8 * i) * DD + k0 + tx] = f2bf(tile[tx][ty + 8 * i]);
}

// ====================== QKV GEMM (128x128 tile, 32x32x16 MFMA) ======================
// 8 mfma_32x32x16 per k-step (vs 16 of 16x16x32): same FLOP/DS, half issue slots.
// z<2 (Q,K): D = W x^T (rows = out_n) -> 4 consecutive dh per reg-quad (uint2 store).
// z==2 (V): D = x W (rows = s) -> 4 consecutive s per reg-quad into Vt (uint2 store).
__global__ __launch_bounds__(256) void qkv_gemm(
    const unsigned short* __restrict__ xb,
    const unsigned short* __restrict__ WtBase,
    const float* __restrict__ bq, const float* __restrict__ bk, const float* __restrict__ bv,
    unsigned short* __restrict__ Qb, unsigned short* __restrict__ Kb, unsigned short* __restrict__ Vt)
{
    __shared__ __align__(16) unsigned short Ald[2][128 * 32];
    __shared__ __align__(16) unsigned short Bld[2][128 * 32];

    const int z = blockIdx.z;
    const unsigned short* Wt = WtBase + (size_t)z * DD * DD;
    const float* bias = (z == 0) ? bq : (z == 1) ? bk : bv;

    const int m0g = blockIdx.y * 128;
    const int n0g = blockIdx.x * 128;
    const int wave = threadIdx.x >> 6, lane = threadIdx.x & 63;
    const int l31 = lane & 31, hf = lane >> 5;
    const int mb = (wave & 1) * 64, nb = (wave >> 1) * 64;

    f32x16 acc[2][2];
    #pragma unroll
    for (int i = 0; i < 2; ++i)
        #pragma unroll
        for (int j = 0; j < 2; ++j)
            #pragma unroll
            for (int r = 0; r < 16; ++r) acc[i][j][r] = 0.f;

    auto stage = [&](int ks, int bf) {
        #pragma unroll
        for (int i = 0; i < 4; ++i) {
            int j = wave * 4 + i;
            if (j < 8) { // A: xb rows m0g..m0g+127
                int bi = j * 64 + lane;
                int row = bi >> 2, p = (bi & 3) ^ (row & 3);
                gl16(xb + (size_t)(m0g + row) * DD + ks + p * 8, &Ald[bf][j * 512]);
            } else {     // B: Wt rows n0g..n0g+127
                int jj = j - 8;
                int bi = jj * 64 + lane;
                int row = bi >> 2, p = (bi & 3) ^ (row & 3);
                gl16(Wt + (size_t)(n0g + row) * DD + ks + p * 8, &Bld[bf][jj * 512]);
            }
        }
    };

    stage(0, 0);
    __syncthreads();

    for (int kk = 0; kk < 32; ++kk) {
        int bf = kk & 1;
        if (kk + 1 < 32) stage((kk + 1) * 32, (kk + 1) & 1);
        // frags: [tile][k-half]; A/B layout: m/n = lane&31, k = (lane>>5)*8 + j
        bf16x8 xf[2][2], wf[2][2];
        #pragma unroll
        for (int t = 0; t < 2; ++t)
            #pragma unroll
            for (int kh = 0; kh < 2; ++kh) {
                int rowx = mb + t * 32 + l31;
                xf[t][kh] = ld_bf16x8(&Ald[bf][(rowx * 4 + ((kh * 2 + hf) ^ (rowx & 3))) * 8]);
                int roww = nb + t * 32 + l31;
                wf[t][kh] = ld_bf16x8(&Bld[bf][(roww * 4 + ((kh * 2 + hf) ^ (roww & 3))) * 8]);
            }
        if (z < 2) { // D[m=out_n][n=s]
            #pragma unroll
            for (int kh = 0; kh < 2; ++kh)
                #pragma unroll
                for (int i = 0; i < 2; ++i)
                    #pragma unroll
                    for (int j = 0; j < 2; ++j)
                        acc[i][j] = __builtin_amdgcn_mfma_f32_32x32x16_bf16(wf[i][kh], xf[j][kh], acc[i][j], 0, 0, 0);
        } else {     // D[m=s][n=out_n]
            #pragma unroll
            for (int kh = 0; kh < 2; ++kh)
                #pragma unroll
                for (int i = 0; i < 2; ++i)
                    #pragma unroll
                    for (int j = 0; j < 2; ++j)
                        acc[i][j] = __builtin_amdgcn_mfma_f32_32x32x16_bf16(xf[i][kh], wf[j][kh], acc[i][j], 0, 0, 0);
        }
        __syncthreads();
    }

    // C/D: col = lane&31, row = (reg&3) + 8*(reg>>2) + 4*(lane>>5)
    if (z < 2) {
        unsigned short* dst = (z == 0) ? Qb : Kb;
        const float sc = (z == 0) ? QSC : 1.0f;
        #pragma unroll
        for (int i = 0; i < 2; ++i)        // W tile (rows = out_n)
            #pragma unroll
            for (int j = 0; j < 2; ++j) {  // x tile (cols = s)
                int m = m0g + mb + j * 32 + l31;   // global token row
                int b = m >> 11, s = m & (SS - 1);
                #pragma unroll
                for (int q4 = 0; q4 < 4; ++q4) {
                    int on = n0g + nb + i * 32 + q4 * 8 + hf * 4; // 4 consecutive out_n
                    int hh = on >> 6, dh0 = on & 63;
                    float4 bv4 = *(const float4*)&bias[on];
                    uint2 o;
                    o.x = pk2bf((acc[i][j][q4 * 4 + 0] + bv4.x) * sc, (acc[i][j][q4 * 4 + 1] + bv4.y) * sc);
                    o.y = pk2bf((acc[i][j][q4 * 4 + 2] + bv4.z) * sc, (acc[i][j][q4 * 4 + 3] + bv4.w) * sc);
                    *(uint2*)&dst[(((size_t)b * HH + hh) * SS + s) * DHD + dh0] = o;
                }
            }
    } else {
        #pragma unroll
        for (int i = 0; i < 2; ++i)        // x tile (rows = s)
            #pragma unroll
            for (int j = 0; j < 2; ++j) {  // W tile (cols = out_n)
                int on = n0g + nb + j * 32 + l31;
                int hh = on >> 6, dh = on & 63;
                float bvv = bias[on];
                #pragma unroll
                for (int q4 = 0; q4 < 4; ++q4) {
                    int m = m0g + mb + i * 32 + q4 * 8 + hf * 4;  // 4 consecutive tokens
                    int b = m >> 11, s0 = m & (SS - 1);
                    uint2 o;
                    o.x = pk2bf(acc[i][j][q4 * 4 + 0] + bvv, acc[i][j][q4 * 4 + 1] + bvv);
                    o.y = pk2bf(acc[i][j][q4 * 4 + 2] + bvv, acc[i][j][q4 * 4 + 3] + bvv);
                    *(uint2*)&Vt[(((size_t)b * HH + hh) * DHD + dh) * SS + s0] = o;
                }
            }
    }
}

// ====================== attention v7 (reverted: best measured 56.2 us) ======================
// block = 512 threads (8 waves), 128 q-rows; wave owns 16 rows over ALL 2048 keys.
__global__ __launch_bounds__(512, 4) void attn(
    const unsigned short* __restrict__ Qb,
    const unsigned short* __restrict__ Kb,
    const unsigned short* __restrict__ Vt,
    unsigned short* __restrict__ Ob)
{
    __shared__ __align__(16) unsigned short Kld[2][64 * 64]; // keys x dh, swizzled blocks
    __shared__ __align__(16) unsigned short Vld[2][64 * 64]; // dh x keys, swizzled blocks
    __shared__ __align__(16) unsigned short tb[8][16 * 68];  // [wave][row(lcol)][key], stride 68

    const int g = blockIdx.y * gridDim.x + blockIdx.x;  // grid (16, 32) = 512
    const int bh = (g & 7) * 4 + ((g >> 3) & 3);        // fixed g%32 per bh -> fixed XCD
    const int qt = g >> 5;                               // 0..15
    const int b = bh >> 4, h = bh & (HH - 1);
    const unsigned short* Qbh = Qb + (size_t)bh * SS * DHD;
    const unsigned short* Kbh = Kb + (size_t)bh * SS * DHD;
    const unsigned short* Vbh = Vt + (size_t)bh * DHD * SS;

    const int wave = threadIdx.x >> 6, lane = threadIdx.x & 63;
    const int quad = lane >> 4, lcol = lane & 15;
    const int rowbase = qt * 128 + wave * 16;

    // Q B-frags (n = q-row, k = dh); 0.125*log2e folded into Q
    bf16x8 qf0 = ld_bf16x8(Qbh + (size_t)(rowbase + lcol) * DHD + quad * 8);
    bf16x8 qf1 = ld_bf16x8(Qbh + (size_t)(rowbase + lcol) * DHD + 32 + quad * 8);

    auto stage = [&](int c, int bf) {
        int kb = c * 64;
        #pragma unroll
        for (int i = 0; i < 2; ++i) {
            int j = wave * 2 + i;
            if (j < 8) { // K: rows = keys, 8 parts of dh
                int bi = j * 64 + lane;
                int r = bi >> 3, p = (bi & 7) ^ (r & 7);
                gl16(Kbh + (size_t)(kb + r) * DHD + p * 8, &Kld[bf][j * 512]);
            } else {     // V: rows = dh, 8 parts of keys
                int jj = j - 8;
                int bi = jj * 64 + lane;
                int dh = bi >> 3, p = (bi & 7) ^ (dh & 7);
                gl16(Vbh + (size_t)dh * SS + kb + p * 8, &Vld[bf][jj * 512]);
            }
        }
    };

    // ---- prologue: stage chunk 0, wave-uniform m0 estimate from it ----
    stage(0, 0);
    __syncthreads();

    float m0 = -1e30f;
    #pragma unroll
    for (int kt = 0; kt < 4; ++kt) {
        int r0 = kt * 16 + lcol;
        bf16x8 ka0 = ld_bf16x8(&Kld[0][(r0 * 8 + (quad ^ (r0 & 7))) * 8]);
        bf16x8 ka1 = ld_bf16x8(&Kld[0][(r0 * 8 + ((quad + 4) ^ (r0 & 7))) * 8]);
        f32x4 s = (f32x4){0.f, 0.f, 0.f, 0.f};
        s = __builtin_amdgcn_mfma_f32_16x16x32_bf16(ka0, qf0, s, 0, 0, 0);
        s = __builtin_amdgcn_mfma_f32_16x16x32_bf16(ka1, qf1, s, 0, 0, 0);
        #pragma unroll
        for (int r = 0; r < 4; ++r) m0 = fmaxf(m0, s[r]);
    }
    #pragma unroll
    for (int msk = 1; msk < 64; msk <<= 1) m0 = fmaxf(m0, __shfl_xor(m0, msk, 64));
    const f32x4 minit = (f32x4){-m0, -m0, -m0, -m0};

    // ---- main loop over 32 chunks of 64 keys ----
    f32x4 oacc[4];
    #pragma unroll
    for (int nt = 0; nt < 4; ++nt) oacc[nt] = (f32x4){0.f, 0.f, 0.f, 0.f};
    float ps = 0.f;

    for (int c = 0; c < 32; ++c) {
        int bf = c & 1;
        if (c + 1 < 32) stage(c + 1, (c + 1) & 1);

        // S^T = K.Q^T (C-init = -m0) -> exp2 -> packed b64 write into tbuf
        #pragma unroll
        for (int kt = 0; kt < 4; ++kt) {
            int r0 = kt * 16 + lcol;
            bf16x8 ka0 = ld_bf16x8(&Kld[bf][(r0 * 8 + (quad ^ (r0 & 7))) * 8]);
            bf16x8 ka1 = ld_bf16x8(&Kld[bf][(r0 * 8 + ((quad + 4) ^ (r0 & 7))) * 8]);
            f32x4 s = minit;
            s = __builtin_amdgcn_mfma_f32_16x16x32_bf16(ka0, qf0, s, 0, 0, 0);
            s = __builtin_amdgcn_mfma_f32_16x16x32_bf16(ka1, qf1, s, 0, 0, 0);
            float e0 = EXP2(s[0]), e1 = EXP2(s[1]);
            float e2 = EXP2(s[2]), e3 = EXP2(s[3]);
            ps += (e0 + e1) + (e2 + e3);
            *(uint2*)&tb[wave][lcol * 68 + kt * 16 + quad * 4] =
                make_uint2(pk2bf(e0, e1), pk2bf(e2, e3));
        }

        // PV: A = P (from tbuf, wave-private, DS in-order), B = V (from Vld)
        #pragma unroll
        for (int kf2 = 0; kf2 < 2; ++kf2) {
            bf16x8 pa = *(const bf16x8*)&tb[wave][lcol * 68 + kf2 * 32 + quad * 8];
            #pragma unroll
            for (int nt = 0; nt < 4; ++nt) {
                int dh = nt * 16 + lcol;
                bf16x8 vb = ld_bf16x8(&Vld[bf][(dh * 8 + ((kf2 * 4 + quad) ^ (dh & 7))) * 8]);
                oacc[nt] = __builtin_amdgcn_mfma_f32_16x16x32_bf16(pa, vb, oacc[nt], 0, 0, 0);
            }
        }
        __syncthreads();
    }

    // ---- epilogue: per-row normalize (rows owned entirely by this wave) ----
    ps += __shfl_xor(ps, 16, 64);
    ps += __shfl_xor(ps, 32, 64);
    float inv = 1.0f / ps;   // valid at lanes where lcol == q-row
    #pragma unroll
    for (int r = 0; r < 4; ++r) {
        float iv = __shfl(inv, quad * 4 + r, 64);
        int srow = rowbase + quad * 4 + r;
        size_t base = (((size_t)b * SS + srow) * HH + h) * DHD;
        #pragma unroll
        for (int nt = 0; nt < 4; ++nt)
            Ob[base + nt * 16 + lcol] = f2bf(oacc[nt][r] * iv);
    }
}

// ====================== output GEMM (64x128 tile, 512 blocks) ======================
__global__ __launch_bounds__(256) void out_gemm(
    const unsigned short* __restrict__ Ob,
    const unsigned short* __restrict__ Wto,
    const float* __restrict__ bo,
    float* __restrict__ out)
{
    __shared__ __align__(16) unsigned short Ald[2][64 * 32];
    __shared__ __align__(16) unsigned short Bld[2][128 * 32];

    const int m0g = blockIdx.y * 64;
    const int n0g = blockIdx.x * 128;
    const int wave = threadIdx.x >> 6, lane = threadIdx.x & 63;
    const int quad = lane >> 4, lcol = lane & 15;
    const int nb = wave * 32;

    f32x4 acc[4][2];
    #pragma unroll
    for (int i = 0; i < 4; ++i)
        #pragma unroll
        for (int j = 0; j < 2; ++j) acc[i][j] = (f32x4){0.f, 0.f, 0.f, 0.f};

    auto stage = [&](int ks, int bf) {
        #pragma unroll
        for (int i = 0; i < 3; ++i) {
            int j = wave * 3 + i;
            if (j < 4) { // A: Ob rows m0g..m0g+63
                int bi = j * 64 + lane;
                int row = bi >> 2, p = (bi & 3) ^ (row & 3);
                gl16(Ob + (size_t)(m0g + row) * DD + ks + p * 8, &Ald[bf][j * 512]);
            } else {     // B: Wto rows n0g..n0g+127
                int jj = j - 4;
                int bi = jj * 64 + lane;
                int row = bi >> 2, p = (bi & 3) ^ (row & 3);
                gl16(Wto + (size_t)(n0g + row) * DD + ks + p * 8, &Bld[bf][jj * 512]);
            }
        }
    };

    stage(0, 0);
    __syncthreads();

    for (int kk = 0; kk < 32; ++kk) {
        int bf = kk & 1;
        if (kk + 1 < 32) stage((kk + 1) * 32, (kk + 1) & 1);
        bf16x8 af[4], bfr[2];
        #pragma unroll
        for (int mt = 0; mt < 4; ++mt) {
            int row = mt * 16 + lcol;
            af[mt] = ld_bf16x8(&Ald[bf][(row * 4 + (quad ^ (row & 3))) * 8]);
        }
        #pragma unroll
        for (int nt = 0; nt < 2; ++nt) {
            int row = nb + nt * 16 + lcol;
            bfr[nt] = ld_bf16x8(&Bld[bf][(row * 4 + (quad ^ (row & 3))) * 8]);
        }
        #pragma unroll
        for (int mt = 0; mt < 4; ++mt)
            #pragma unroll
            for (int nt = 0; nt < 2; ++nt)
                acc[mt][nt] = __builtin_amdgcn_mfma_f32_16x16x32_bf16(af[mt], bfr[nt], acc[mt][nt], 0, 0, 0);
        __syncthreads();
    }

    #pragma unroll
    for (int mt = 0; mt < 4; ++mt)
        #pragma unroll
        for (int nt = 0; nt < 2; ++nt) {
            int n = n0g + nb + nt * 16 + lcol;
            float bv_ = bo[n];
            #pragma unroll
            for (int r = 0; r < 4; ++r) {
                int m = m0g + mt * 16 + quad * 4 + r;
                out[(size_t)m * DD + n] = acc[mt][nt][r] + bv_;
            }
        }
}

extern "C" void kernel_launch(void* const* d_in, const int* in_sizes, int n_in,
                              void* d_out, int out_size, void* d_ws, size_t ws_size,
                              hipStream_t stream)
{
    const float* x  = (const float*)d_in[0];
    const float* Wq = (const float*)d_in[1];
    const float* bq = (const float*)d_in[2];
    const float* Wk = (const float*)d_in[3];
    const float* bk = (const float*)d_in[4];
    const float* Wv = (const float*)d_in[5];
    const float* bv = (const float*)d_in[6];
    const float* Wo = (const float*)d_in[7];
    const float* bo = (const float*)d_in[8];
    float* out = (float*)d_out;

    unsigned short* ws = (unsigned short*)d_ws;
    unsigned short* Wt  = ws;                        // 4 * D*D (q,k,v,o)
    unsigned short* Wto = Wt + 3 * (size_t)DD * DD;
    unsigned short* Qb  = Wt + 4 * (size_t)DD * DD;  // M*D each
    unsigned short* Kb  = Qb + (size_t)MM * DD;
    unsigned short* Vt  = Kb + (size_t)MM * DD;
    unsigned short* xb  = Vt + (size_t)MM * DD;      // total 40 MB
    unsigned short* Ob  = xb;                        // alias: xb dead after qkv_gemm

    prep<<<8192, 256, 0, stream>>>(x, xb, Wq, Wk, Wv, Wo, Wt);

    qkv_gemm<<<dim3(DD / 128, MM / 128, 3), 256, 0, stream>>>(xb, Wt, bq, bk, bv, Qb, Kb, Vt);

    attn<<<dim3(16, 32), 512, 0, stream>>>(Qb, Kb, Vt, Ob);

    out_gemm<<<dim3(DD / 128, MM / 64), 256, 0, stream>>>(Ob, Wto, bo, out);
}

// Round 10
// 203.287 us; speedup vs baseline: 1.0988x; 1.0988x over previous
//
#include <hip/hip_runtime.h>
#include <hip/hip_bf16.h>

#define DEV __device__ __forceinline__

typedef short bf16x8 __attribute__((ext_vector_type(8)));
typedef float f32x4 __attribute__((ext_vector_type(4)));
typedef unsigned int u32;

constexpr int BB = 2, SS = 2048, DD = 1024, HH = 16, DHD = 64;
constexpr int MM = BB * SS; // 4096
#define QSC 0.1803368801111f  /* 0.125 * log2(e): scores in log2 domain */

#if __has_builtin(__builtin_amdgcn_exp2f)
#define EXP2(x) __builtin_amdgcn_exp2f(x)
#else
#define EXP2(x) exp2f(x)
#endif

// round-half-up bf16; bias only at exact-half cases
DEV unsigned short f2bf(float f) {
    union { float f; unsigned int u; } v; v.f = f;
    return (unsigned short)((v.u + 0x8000u) >> 16);
}
// pack two f32 -> (bf16(b)<<16)|bf16(a) : add, add, v_perm = 3 instr
#if __has_builtin(__builtin_amdgcn_perm)
DEV u32 pk2bf(float a, float b) {
    union { float f; u32 u; } ua, ub; ua.f = a; ub.f = b;
    return __builtin_amdgcn_perm(ub.u + 0x8000u, ua.u + 0x8000u, 0x07060302u);
}
#else
DEV u32 pk2bf(float a, float b) {
    union { float f; u32 u; } ua, ub; ua.f = a; ub.f = b;
    return ((ua.u + 0x8000u) >> 16) | ((ub.u + 0x8000u) & 0xffff0000u);
}
#endif

DEV bf16x8 ld_bf16x8(const unsigned short* p) { return *(const bf16x8*)p; }

// async global->LDS, 16B per lane; lds dest = wave-uniform base + lane*16
DEV void gl16(const unsigned short* g, unsigned short* l) {
    __builtin_amdgcn_global_load_lds(
        (const __attribute__((address_space(1))) u32*)g,
        (__attribute__((address_space(3))) u32*)l, 16, 0, 0);
}

// ---- prep (fused): blocks [0,4096) = x->bf16 ; [4096,8192) = W transposes ----
__global__ void prep(const float* __restrict__ x, unsigned short* __restrict__ xb,
                     const float* __restrict__ W0, const float* __restrict__ W1,
                     const float* __restrict__ W2, const float* __restrict__ W3,
                     unsigned short* __restrict__ WtBase) {
    __shared__ float tile[32][33];
    int blk = blockIdx.x;
    if (blk < 4096) {
        int i = blk * 256 + threadIdx.x;
        float4 v = ((const float4*)x)[i];
        uint2 o;
        o.x = pk2bf(v.x, v.y);
        o.y = pk2bf(v.z, v.w);
        ((uint2*)xb)[i] = o;
        return;
    }
    blk -= 4096;                 // 4 weights x 1024 tiles
    int wsel = blk >> 10;
    const float* W = (wsel == 0) ? W0 : (wsel == 1) ? W1 : (wsel == 2) ? W2 : W3;
    unsigned short* Wt = WtBase + (size_t)wsel * DD * DD;
    int t = blk & 1023;
    int n0 = (t & 31) * 32, k0 = (t >> 5) * 32;
    int tx = threadIdx.x & 31, ty = threadIdx.x >> 5; // 32 x 8
    #pragma unroll
    for (int i = 0; i < 4; ++i)
        tile[ty + 8 * i][tx] = W[(size_t)(k0 + ty + 8 * i) * DD + n0 + tx];
    __syncthreads();
    #pragma unroll
    for (int i = 0; i < 4; ++i)
        Wt[(size_t)(n0 + ty + 8 * i) * DD + k0 + tx] = f2bf(tile[tx][ty + 8 * i]);
}

// ====================== QKV GEMM (R7 version: 128x128 tile, 16x16x32) ======================
__global__ __launch_bounds__(256) void qkv_gemm(
    const unsigned short* __restrict__ xb,
    const unsigned short* __restrict__ WtBase,
    const float* __restrict__ bq, const float* __restrict__ bk, const float* __restrict__ bv,
    unsigned short* __restrict__ Qb, unsigned short* __restrict__ Kb, unsigned short* __restrict__ Vt)
{
    __shared__ __align__(16) unsigned short Ald[2][128 * 32];
    __shared__ __align__(16) unsigned short Bld[2][128 * 32];

    const int z = blockIdx.z;
    const unsigned short* Wt = WtBase + (size_t)z * DD * DD;
    const float* bias = (z == 0) ? bq : (z == 1) ? bk : bv;

    const int m0g = blockIdx.y * 128;
    const int n0g = blockIdx.x * 128;
    const int wave = threadIdx.x >> 6, lane = threadIdx.x & 63;
    const int quad = lane >> 4, lcol = lane & 15;
    const int mb = (wave & 1) * 64, nb = (wave >> 1) * 64;

    f32x4 acc[4][4];
    #pragma unroll
    for (int i = 0; i < 4; ++i)
        #pragma unroll
        for (int j = 0; j < 4; ++j) acc[i][j] = (f32x4){0.f, 0.f, 0.f, 0.f};

    auto stage = [&](int ks, int bf) {
        #pragma unroll
        for (int i = 0; i < 4; ++i) {
            int j = wave * 4 + i;
            if (j < 8) { // A: xb rows m0g..m0g+127
                int bi = j * 64 + lane;
                int row = bi >> 2, p = (bi & 3) ^ (row & 3);
                gl16(xb + (size_t)(m0g + row) * DD + ks + p * 8, &Ald[bf][j * 512]);
            } else {     // B: Wt rows n0g..n0g+127
                int jj = j - 8;
                int bi = jj * 64 + lane;
                int row = bi >> 2, p = (bi & 3) ^ (row & 3);
                gl16(Wt + (size_t)(n0g + row) * DD + ks + p * 8, &Bld[bf][jj * 512]);
            }
        }
    };

    stage(0, 0);
    __syncthreads();

    for (int kk = 0; kk < 32; ++kk) {
        int bf = kk & 1;
        if (kk + 1 < 32) stage((kk + 1) * 32, (kk + 1) & 1);
        bf16x8 af[4], bfr[4];
        #pragma unroll
        for (int mt = 0; mt < 4; ++mt) {
            int row = mb + mt * 16 + lcol;
            af[mt] = ld_bf16x8(&Ald[bf][(row * 4 + (quad ^ (row & 3))) * 8]);
        }
        #pragma unroll
        for (int nt = 0; nt < 4; ++nt) {
            int row = nb + nt * 16 + lcol;
            bfr[nt] = ld_bf16x8(&Bld[bf][(row * 4 + (quad ^ (row & 3))) * 8]);
        }
        if (z < 2) { // transposed product: D[m=out_n][n=s]
            #pragma unroll
            for (int mt = 0; mt < 4; ++mt)
                #pragma unroll
                for (int nt = 0; nt < 4; ++nt)
                    acc[mt][nt] = __builtin_amdgcn_mfma_f32_16x16x32_bf16(bfr[nt], af[mt], acc[mt][nt], 0, 0, 0);
        } else {
            #pragma unroll
            for (int mt = 0; mt < 4; ++mt)
                #pragma unroll
                for (int nt = 0; nt < 4; ++nt)
                    acc[mt][nt] = __builtin_amdgcn_mfma_f32_16x16x32_bf16(af[mt], bfr[nt], acc[mt][nt], 0, 0, 0);
        }
        __syncthreads();
    }

    if (z < 2) {
        unsigned short* dst = (z == 0) ? Qb : Kb;
        const float sc = (z == 0) ? QSC : 1.0f;
        #pragma unroll
        for (int mt = 0; mt < 4; ++mt)
            #pragma unroll
            for (int nt = 0; nt < 4; ++nt) {
                int m = m0g + mb + mt * 16 + lcol;        // global row -> (b,s)
                int nbt = n0g + nb + nt * 16 + quad * 4;  // 4 consecutive out_n
                int b = m >> 11, s = m & (SS - 1);
                int h = nbt >> 6, dh0 = nbt & 63;
                float4 bv4 = *(const float4*)&bias[nbt];
                uint2 o;
                o.x = pk2bf((acc[mt][nt][0] + bv4.x) * sc, (acc[mt][nt][1] + bv4.y) * sc);
                o.y = pk2bf((acc[mt][nt][2] + bv4.z) * sc, (acc[mt][nt][3] + bv4.w) * sc);
                *(uint2*)&dst[(((size_t)b * HH + h) * SS + s) * DHD + dh0] = o;
            }
    } else {
        #pragma unroll
        for (int mt = 0; mt < 4; ++mt)
            #pragma unroll
            for (int nt = 0; nt < 4; ++nt) {
                int n = n0g + nb + nt * 16 + lcol;        // out_n
                int mbt = m0g + mb + mt * 16 + quad * 4;  // 4 consecutive global rows
                int h = n >> 6, dh = n & 63;
                int b = mbt >> 11, s0 = mbt & (SS - 1);
                float bvv = bias[n];
                uint2 o;
                o.x = pk2bf(acc[mt][nt][0] + bvv, acc[mt][nt][1] + bvv);
                o.y = pk2bf(acc[mt][nt][2] + bvv, acc[mt][nt][3] + bvv);
                *(uint2*)&Vt[(((size_t)b * HH + h) * DHD + dh) * SS + s0] = o;
            }
    }
}

// ====================== attention v7 (best measured 56.2 us, unchanged) ======================
__global__ __launch_bounds__(512, 4) void attn(
    const unsigned short* __restrict__ Qb,
    const unsigned short* __restrict__ Kb,
    const unsigned short* __restrict__ Vt,
    unsigned short* __restrict__ Ob)
{
    __shared__ __align__(16) unsigned short Kld[2][64 * 64]; // keys x dh, swizzled blocks
    __shared__ __align__(16) unsigned short Vld[2][64 * 64]; // dh x keys, swizzled blocks
    __shared__ __align__(16) unsigned short tb[8][16 * 68];  // [wave][row(lcol)][key], stride 68

    const int g = blockIdx.y * gridDim.x + blockIdx.x;  // grid (16, 32) = 512
    const int bh = (g & 7) * 4 + ((g >> 3) & 3);        // fixed g%32 per bh -> fixed XCD
    const int qt = g >> 5;                               // 0..15
    const int b = bh >> 4, h = bh & (HH - 1);
    const unsigned short* Qbh = Qb + (size_t)bh * SS * DHD;
    const unsigned short* Kbh = Kb + (size_t)bh * SS * DHD;
    const unsigned short* Vbh = Vt + (size_t)bh * DHD * SS;

    const int wave = threadIdx.x >> 6, lane = threadIdx.x & 63;
    const int quad = lane >> 4, lcol = lane & 15;
    const int rowbase = qt * 128 + wave * 16;

    // Q B-frags (n = q-row, k = dh); 0.125*log2e folded into Q
    bf16x8 qf0 = ld_bf16x8(Qbh + (size_t)(rowbase + lcol) * DHD + quad * 8);
    bf16x8 qf1 = ld_bf16x8(Qbh + (size_t)(rowbase + lcol) * DHD + 32 + quad * 8);

    auto stage = [&](int c, int bf) {
        int kb = c * 64;
        #pragma unroll
        for (int i = 0; i < 2; ++i) {
            int j = wave * 2 + i;
            if (j < 8) { // K: rows = keys, 8 parts of dh
                int bi = j * 64 + lane;
                int r = bi >> 3, p = (bi & 7) ^ (r & 7);
                gl16(Kbh + (size_t)(kb + r) * DHD + p * 8, &Kld[bf][j * 512]);
            } else {     // V: rows = dh, 8 parts of keys
                int jj = j - 8;
                int bi = jj * 64 + lane;
                int dh = bi >> 3, p = (bi & 7) ^ (dh & 7);
                gl16(Vbh + (size_t)dh * SS + kb + p * 8, &Vld[bf][jj * 512]);
            }
        }
    };

    // ---- prologue: stage chunk 0, wave-uniform m0 estimate from it ----
    stage(0, 0);
    __syncthreads();

    float m0 = -1e30f;
    #pragma unroll
    for (int kt = 0; kt < 4; ++kt) {
        int r0 = kt * 16 + lcol;
        bf16x8 ka0 = ld_bf16x8(&Kld[0][(r0 * 8 + (quad ^ (r0 & 7))) * 8]);
        bf16x8 ka1 = ld_bf16x8(&Kld[0][(r0 * 8 + ((quad + 4) ^ (r0 & 7))) * 8]);
        f32x4 s = (f32x4){0.f, 0.f, 0.f, 0.f};
        s = __builtin_amdgcn_mfma_f32_16x16x32_bf16(ka0, qf0, s, 0, 0, 0);
        s = __builtin_amdgcn_mfma_f32_16x16x32_bf16(ka1, qf1, s, 0, 0, 0);
        #pragma unroll
        for (int r = 0; r < 4; ++r) m0 = fmaxf(m0, s[r]);
    }
    #pragma unroll
    for (int msk = 1; msk < 64; msk <<= 1) m0 = fmaxf(m0, __shfl_xor(m0, msk, 64));
    const f32x4 minit = (f32x4){-m0, -m0, -m0, -m0};

    // ---- main loop over 32 chunks of 64 keys ----
    f32x4 oacc[4];
    #pragma unroll
    for (int nt = 0; nt < 4; ++nt) oacc[nt] = (f32x4){0.f, 0.f, 0.f, 0.f};
    float ps = 0.f;

    for (int c = 0; c < 32; ++c) {
        int bf = c & 1;
        if (c + 1 < 32) stage(c + 1, (c + 1) & 1);

        // S^T = K.Q^T (C-init = -m0) -> exp2 -> packed b64 write into tbuf
        #pragma unroll
        for (int kt = 0; kt < 4; ++kt) {
            int r0 = kt * 16 + lcol;
            bf16x8 ka0 = ld_bf16x8(&Kld[bf][(r0 * 8 + (quad ^ (r0 & 7))) * 8]);
            bf16x8 ka1 = ld_bf16x8(&Kld[bf][(r0 * 8 + ((quad + 4) ^ (r0 & 7))) * 8]);
            f32x4 s = minit;
            s = __builtin_amdgcn_mfma_f32_16x16x32_bf16(ka0, qf0, s, 0, 0, 0);
            s = __builtin_amdgcn_mfma_f32_16x16x32_bf16(ka1, qf1, s, 0, 0, 0);
            float e0 = EXP2(s[0]), e1 = EXP2(s[1]);
            float e2 = EXP2(s[2]), e3 = EXP2(s[3]);
            ps += (e0 + e1) + (e2 + e3);
            *(uint2*)&tb[wave][lcol * 68 + kt * 16 + quad * 4] =
                make_uint2(pk2bf(e0, e1), pk2bf(e2, e3));
        }

        // PV: A = P (from tbuf, wave-private, DS in-order), B = V (from Vld)
        #pragma unroll
        for (int kf2 = 0; kf2 < 2; ++kf2) {
            bf16x8 pa = *(const bf16x8*)&tb[wave][lcol * 68 + kf2 * 32 + quad * 8];
            #pragma unroll
            for (int nt = 0; nt < 4; ++nt) {
                int dh = nt * 16 + lcol;
                bf16x8 vb = ld_bf16x8(&Vld[bf][(dh * 8 + ((kf2 * 4 + quad) ^ (dh & 7))) * 8]);
                oacc[nt] = __builtin_amdgcn_mfma_f32_16x16x32_bf16(pa, vb, oacc[nt], 0, 0, 0);
            }
        }
        __syncthreads();
    }

    // ---- epilogue: per-row normalize (rows owned entirely by this wave) ----
    ps += __shfl_xor(ps, 16, 64);
    ps += __shfl_xor(ps, 32, 64);
    float inv = 1.0f / ps;   // valid at lanes where lcol == q-row
    #pragma unroll
    for (int r = 0; r < 4; ++r) {
        float iv = __shfl(inv, quad * 4 + r, 64);
        int srow = rowbase + quad * 4 + r;
        size_t base = (((size_t)b * SS + srow) * HH + h) * DHD;
        #pragma unroll
        for (int nt = 0; nt < 4; ++nt)
            Ob[base + nt * 16 + lcol] = f2bf(oacc[nt][r] * iv);
    }
}

// ====================== output GEMM v2 ======================
// Tile 64 tokens x 128 out_n, BK=64 dbuf (16 barriers), transposed product:
// A = Wto (rows = out_n), B = Ob (rows = tokens) -> D[m=out_n][n=token];
// reg-quad r gives 4 consecutive out_n -> float4 stores (8 per thread).
// LDS frag swizzle = attn Kld 8-part scheme (measured 0 conflicts).
__global__ __launch_bounds__(256) void out_gemm(
    const unsigned short* __restrict__ Ob,
    const unsigned short* __restrict__ Wto,
    const float* __restrict__ bo,
    float* __restrict__ out)
{
    __shared__ __align__(16) unsigned short Wld[2][128 * 64]; // out_n x k
    __shared__ __align__(16) unsigned short Old[2][64 * 64];  // token x k

    const int m0g = blockIdx.y * 64;    // tokens
    const int n0g = blockIdx.x * 128;   // out_n
    const int wave = threadIdx.x >> 6, lane = threadIdx.x & 63;
    const int quad = lane >> 4, lcol = lane & 15;
    const int nb = wave * 32;           // wave's out_n sub-range

    f32x4 acc[2][4];
    #pragma unroll
    for (int i = 0; i < 2; ++i)
        #pragma unroll
        for (int j = 0; j < 4; ++j) acc[i][j] = (f32x4){0.f, 0.f, 0.f, 0.f};

    auto stage = [&](int ks, int bf) {
        #pragma unroll
        for (int i = 0; i < 6; ++i) {
            int j = wave * 6 + i;
            if (j < 16) { // W: 128 rows x 8 parts
                int bi = j * 64 + lane;
                int r = bi >> 3, p = (bi & 7) ^ (r & 7);
                gl16(Wto + (size_t)(n0g + r) * DD + ks + p * 8, &Wld[bf][j * 512]);
            } else {      // Ob: 64 rows x 8 parts
                int jj = j - 16;
                int bi = jj * 64 + lane;
                int r = bi >> 3, p = (bi & 7) ^ (r & 7);
                gl16(Ob + (size_t)(m0g + r) * DD + ks + p * 8, &Old[bf][jj * 512]);
            }
        }
    };

    stage(0, 0);
    __syncthreads();

    for (int kk = 0; kk < 16; ++kk) {
        int bf = kk & 1;
        if (kk + 1 < 16) stage((kk + 1) * 64, (kk + 1) & 1);
        #pragma unroll
        for (int kh = 0; kh < 2; ++kh) {
            bf16x8 wf[2], of[4];
            #pragma unroll
            for (int i = 0; i < 2; ++i) {
                int row = nb + i * 16 + lcol;
                wf[i] = ld_bf16x8(&Wld[bf][(row * 8 + ((kh * 4 + quad) ^ (row & 7))) * 8]);
            }
            #pragma unroll
            for (int j = 0; j < 4; ++j) {
                int row = j * 16 + lcol;
                of[j] = ld_bf16x8(&Old[bf][(row * 8 + ((kh * 4 + quad) ^ (row & 7))) * 8]);
            }
            #pragma unroll
            for (int i = 0; i < 2; ++i)
                #pragma unroll
                for (int j = 0; j < 4; ++j)
                    acc[i][j] = __builtin_amdgcn_mfma_f32_16x16x32_bf16(wf[i], of[j], acc[i][j], 0, 0, 0);
        }
        __syncthreads();
    }

    // C: col = token (lcol within j-tile), row = out_n (quad*4 + r, consecutive)
    #pragma unroll
    for (int i = 0; i < 2; ++i) {
        int n4 = n0g + nb + i * 16 + quad * 4;
        float4 bv4 = *(const float4*)&bo[n4];
        #pragma unroll
        for (int j = 0; j < 4; ++j) {
            int token = m0g + j * 16 + lcol;
            float4 o;
            o.x = acc[i][j][0] + bv4.x;
            o.y = acc[i][j][1] + bv4.y;
            o.z = acc[i][j][2] + bv4.z;
            o.w = acc[i][j][3] + bv4.w;
            *(float4*)&out[(size_t)token * DD + n4] = o;
        }
    }
}

extern "C" void kernel_launch(void* const* d_in, const int* in_sizes, int n_in,
                              void* d_out, int out_size, void* d_ws, size_t ws_size,
                              hipStream_t stream)
{
    const float* x  = (const float*)d_in[0];
    const float* Wq = (const float*)d_in[1];
    const float* bq = (const float*)d_in[2];
    const float* Wk = (const float*)d_in[3];
    const float* bk = (const float*)d_in[4];
    const float* Wv = (const float*)d_in[5];
    const float* bv = (const float*)d_in[6];
    const float* Wo = (const float*)d_in[7];
    const float* bo = (const float*)d_in[8];
    float* out = (float*)d_out;

    unsigned short* ws = (unsigned short*)d_ws;
    unsigned short* Wt  = ws;                        // 4 * D*D (q,k,v,o)
    unsigned short* Wto = Wt + 3 * (size_t)DD * DD;
    unsigned short* Qb  = Wt + 4 * (size_t)DD * DD;  // M*D each
    unsigned short* Kb  = Qb + (size_t)MM * DD;
    unsigned short* Vt  = Kb + (size_t)MM * DD;
    unsigned short* xb  = Vt + (size_t)MM * DD;      // total 40 MB
    unsigned short* Ob  = xb;                        // alias: xb dead after qkv_gemm

    prep<<<8192, 256, 0, stream>>>(x, xb, Wq, Wk, Wv, Wo, Wt);

    qkv_gemm<<<dim3(DD / 128, MM / 128, 3), 256, 0, stream>>>(xb, Wt, bq, bk, bv, Qb, Kb, Vt);

    attn<<<dim3(16, 32), 512, 0, stream>>>(Qb, Kb, Vt, Ob);

    out_gemm<<<dim3(DD / 128, MM / 64), 256, 0, stream>>>(Ob, Wto, bo, out);
}